// Round 7
// baseline (872.719 us; speedup 1.0000x reference)
//
#include <hip/hip_runtime.h>

#define BN_EPS 1e-5f

__device__ __forceinline__ void atomicAdd4(float* p, float4 v) {
    unsafeAtomicAdd(p + 0, v.x);
    unsafeAtomicAdd(p + 1, v.y);
    unsafeAtomicAdd(p + 2, v.z);
    unsafeAtomicAdd(p + 3, v.w);
}

__device__ __forceinline__ float bnr1(float a, float b, float v) {
    return fmaxf(fmaf(a, v, b), 0.0f);
}

// ===================== CSR build (once, reused for all 4 layers) ============

__global__ __launch_bounds__(256) void k_count(const int* __restrict__ dst,
        int* __restrict__ deg, int nedges)
{
    int e = blockIdx.x * 256 + threadIdx.x;
    if (e < nedges) atomicAdd(&deg[dst[e]], 1);
}

__global__ __launch_bounds__(256) void k_scanA(const int* __restrict__ deg,
        int* __restrict__ incl, int* __restrict__ bsum, int N)
{
    __shared__ int tmp[256];
    int i = blockIdx.x * 256 + threadIdx.x;
    int d = (i < N) ? deg[i] : 0;
    tmp[threadIdx.x] = d;
    __syncthreads();
    for (int off = 1; off < 256; off <<= 1) {
        int val = (threadIdx.x >= off) ? tmp[threadIdx.x - off] : 0;
        __syncthreads();
        tmp[threadIdx.x] += val;
        __syncthreads();
    }
    if (i < N) incl[i] = tmp[threadIdx.x];
    if (threadIdx.x == 255) bsum[blockIdx.x] = tmp[255];
}

__global__ __launch_bounds__(512) void k_scanB(int* __restrict__ bsum, int NB)
{
    __shared__ int tmp[512];
    int tid = threadIdx.x;
    int d = (tid < NB) ? bsum[tid] : 0;
    tmp[tid] = d;
    __syncthreads();
    for (int off = 1; off < 512; off <<= 1) {
        int val = (tid >= off) ? tmp[tid - off] : 0;
        __syncthreads();
        tmp[tid] += val;
        __syncthreads();
    }
    if (tid < NB) bsum[tid] = tmp[tid] - d;   // exclusive
}

__global__ __launch_bounds__(256) void k_scanC(const int* __restrict__ deg,
        const int* __restrict__ incl, const int* __restrict__ bsum,
        int* __restrict__ rowptr, int* __restrict__ fill, int N)
{
    int i = blockIdx.x * 256 + threadIdx.x;
    if (i >= N) return;
    int d = deg[i];
    int excl = incl[i] - d + bsum[blockIdx.x];
    rowptr[i] = excl;
    fill[i] = excl;
    if (i == N - 1) rowptr[N] = excl + d;
}

// XCD-partitioned fill (R6 win: csr lines dirtied by one XCD slot each)
__global__ __launch_bounds__(256) void k_fill(const int* __restrict__ src,
        const int* __restrict__ dst, int* __restrict__ fillp,
        int* __restrict__ csr, int nedges, int M)
{
    int nx = gridDim.x >> 3;
    int x  = blockIdx.x & 7;
    int ci = blockIdx.x >> 3;
    int lo = (int)(((long long)M * x) >> 3);
    int hi = (int)(((long long)M * (x + 1)) >> 3);
    int chunk = (nedges + nx - 1) / nx;
    int e0 = ci * chunk;
    int e1 = min(nedges, e0 + chunk);
    for (int e = e0 + threadIdx.x; e < e1; e += 256) {
        int d = dst[e];
        if (d >= lo && d < hi) {
            int pos = atomicAdd(&fillp[d], 1);
            csr[pos] = src[e];
        }
    }
}

// ===================== fused gather + GIN combine + Linear1 + stats =========
// U[d] = (1+eps)*val(d) + sum_{s in adj(d)} val(s); val = relu(a*Z+b) or raw x
// V[d][c] = sum_k U[d][k] * W1[k][c] + b1[c];  Sout += colsum/colsumsq of V.
// wave = 1 node at a time (grid-stride). After the butterfly reduce, ALL 64
// lanes hold the full U row (uniform across the 4 sub-groups); lane c keeps
// W1 column c in 64 statically-indexed registers and computes V[.][c].
// All control flow around shfls is wave-uniform (R3 lesson); W column in
// registers with full unroll (rule #20); VGPR ~115 (R4 lesson).
__global__ __launch_bounds__(256) void k_fused(const float4* __restrict__ H,
        const int* __restrict__ rowptr, const int* __restrict__ csr,
        const float* __restrict__ Sin, const float* __restrict__ g,
        const float* __restrict__ bt, const float* __restrict__ epsp,
        int layer, const float* __restrict__ W1, const float* __restrict__ b1,
        float* __restrict__ V, float* __restrict__ Sout, int N, float invM)
{
    int lane = threadIdx.x & 63;
    int wv = threadIdx.x >> 6;
    int q = lane & 15, sub = lane >> 4;

    // W1 column `lane` -> registers (one-time, amortized over ~25 nodes/wave)
    float w[64];
#pragma unroll
    for (int k = 0; k < 64; ++k) w[k] = W1[k * 64 + lane];
    float b1v = b1[lane];
    float e = 1.0f + epsp[layer];

    float4 A4 = make_float4(1.f, 1.f, 1.f, 1.f);
    float4 B4 = make_float4(0.f, 0.f, 0.f, 0.f);
    bool dobn = (Sin != nullptr);
    if (dobn) {
        float as[4], bs[4];
#pragma unroll
        for (int j = 0; j < 4; ++j) {
            int c = q * 4 + j;
            float mu = Sin[c] * invM;
            float var = Sin[64 + c] * invM - mu * mu;
            float a = g[c] * rsqrtf(var + BN_EPS);
            as[j] = a;
            bs[j] = bt[c] - a * mu;
        }
        A4 = make_float4(as[0], as[1], as[2], as[3]);
        B4 = make_float4(bs[0], bs[1], bs[2], bs[3]);
    }

    float sv = 0.f, sq = 0.f;

    for (int node = blockIdx.x * 4 + wv; node < N; node += gridDim.x * 4) {
        int start = rowptr[node], end = rowptr[node + 1];
        float4 acc = make_float4(0.f, 0.f, 0.f, 0.f);

        for (int base = start; base < end; base += 64) {
            int n = min(64, end - base);               // wave-uniform
            int myidx = (lane < n) ? csr[base + lane] : 0;
            int nIter = (n + 15) >> 4;                 // wave-uniform
            for (int t = 0; t < nIter; ++t) {
                int j0 = t * 16 + sub;
                int j1 = j0 + 4, j2 = j0 + 8, j3 = j0 + 12;
                int s0 = __shfl(myidx, (j0 < n) ? j0 : 0);
                int s1 = __shfl(myidx, (j1 < n) ? j1 : 0);
                int s2 = __shfl(myidx, (j2 < n) ? j2 : 0);
                int s3 = __shfl(myidx, (j3 < n) ? j3 : 0);
                float4 v0 = H[(size_t)s0 * 16 + q];
                float4 v1 = H[(size_t)s1 * 16 + q];
                float4 v2 = H[(size_t)s2 * 16 + q];
                float4 v3 = H[(size_t)s3 * 16 + q];
                if (dobn) {
                    v0.x = bnr1(A4.x, B4.x, v0.x); v0.y = bnr1(A4.y, B4.y, v0.y);
                    v0.z = bnr1(A4.z, B4.z, v0.z); v0.w = bnr1(A4.w, B4.w, v0.w);
                    v1.x = bnr1(A4.x, B4.x, v1.x); v1.y = bnr1(A4.y, B4.y, v1.y);
                    v1.z = bnr1(A4.z, B4.z, v1.z); v1.w = bnr1(A4.w, B4.w, v1.w);
                    v2.x = bnr1(A4.x, B4.x, v2.x); v2.y = bnr1(A4.y, B4.y, v2.y);
                    v2.z = bnr1(A4.z, B4.z, v2.z); v2.w = bnr1(A4.w, B4.w, v2.w);
                    v3.x = bnr1(A4.x, B4.x, v3.x); v3.y = bnr1(A4.y, B4.y, v3.y);
                    v3.z = bnr1(A4.z, B4.z, v3.z); v3.w = bnr1(A4.w, B4.w, v3.w);
                }
                if (j0 < n) { acc.x += v0.x; acc.y += v0.y; acc.z += v0.z; acc.w += v0.w; }
                if (j1 < n) { acc.x += v1.x; acc.y += v1.y; acc.z += v1.z; acc.w += v1.w; }
                if (j2 < n) { acc.x += v2.x; acc.y += v2.y; acc.z += v2.z; acc.w += v2.w; }
                if (j3 < n) { acc.x += v3.x; acc.y += v3.y; acc.z += v3.z; acc.w += v3.w; }
            }
        }
        // butterfly: afterwards acc is uniform across the 4 sub-groups
        acc.x += __shfl_xor(acc.x, 16); acc.y += __shfl_xor(acc.y, 16);
        acc.z += __shfl_xor(acc.z, 16); acc.w += __shfl_xor(acc.w, 16);
        acc.x += __shfl_xor(acc.x, 32); acc.y += __shfl_xor(acc.y, 32);
        acc.z += __shfl_xor(acc.z, 32); acc.w += __shfl_xor(acc.w, 32);

        // self term (all lanes; same addr within quad -> cache broadcast)
        float4 hv = H[(size_t)node * 16 + q];
        if (dobn) {
            hv.x = bnr1(A4.x, B4.x, hv.x); hv.y = bnr1(A4.y, B4.y, hv.y);
            hv.z = bnr1(A4.z, B4.z, hv.z); hv.w = bnr1(A4.w, B4.w, hv.w);
        }
        float4 u4;
        u4.x = fmaf(e, hv.x, acc.x); u4.y = fmaf(e, hv.y, acc.y);
        u4.z = fmaf(e, hv.z, acc.z); u4.w = fmaf(e, hv.w, acc.w);

        // row @ W1: u[k] lives in lane k>>2 (comp k&3), broadcast via shfl
        float v = b1v;
#pragma unroll
        for (int kq = 0; kq < 16; ++kq) {
            float ax = __shfl(u4.x, kq);
            float ay = __shfl(u4.y, kq);
            float az = __shfl(u4.z, kq);
            float aw = __shfl(u4.w, kq);
            v = fmaf(ax, w[kq * 4 + 0], v);
            v = fmaf(ay, w[kq * 4 + 1], v);
            v = fmaf(az, w[kq * 4 + 2], v);
            v = fmaf(aw, w[kq * 4 + 3], v);
        }
        V[(size_t)node * 64 + lane] = v;
        sv += v;
        sq += v * v;
    }

    // block-level stats reduce -> 128 global atomics
    __shared__ float SRED[4][128];
    SRED[wv][lane] = sv;
    SRED[wv][64 + lane] = sq;
    __syncthreads();
    int tid = threadIdx.x;
    if (tid < 128) {
        float s = SRED[0][tid] + SRED[1][tid] + SRED[2][tid] + SRED[3][tid];
        unsafeAtomicAdd(&Sout[tid], s);
    }
}

// ===================== GEMM2 + fused column stats ===========================
// Out[r][c] = sum_k relu(a[k]*In[r][k]+b[k]) * W[k][c] + bias[c]
// Sout[0..63] += column sums, Sout[64..127] += column sumsq.
__global__ __launch_bounds__(256) void k_gemm(const float4* __restrict__ In,
        const float* __restrict__ Sin, const float* __restrict__ g,
        const float* __restrict__ bt, const float* __restrict__ W,
        const float* __restrict__ bias, float4* __restrict__ Out,
        float* __restrict__ Sout, int M)
{
    __shared__ float4 Bs[64][16];   // W tile, 16 KB
    __shared__ float As_[64];
    __shared__ float Bb_[64];
    __shared__ float SRED[4][128];
    int tid = threadIdx.x;
    const float4* W4 = (const float4*)W;
#pragma unroll
    for (int i = 0; i < 4; ++i)
        ((float4*)Bs)[tid + 256 * i] = W4[tid + 256 * i];
    if (tid < 64) {
        if (Sin) {
            float invM = 1.0f / (float)M;
            float mu = Sin[tid] * invM;
            float var = Sin[64 + tid] * invM - mu * mu;
            float a = g[tid] * rsqrtf(var + BN_EPS);
            As_[tid] = a;
            Bb_[tid] = bt[tid] - a * mu;
        } else { As_[tid] = 1.f; Bb_[tid] = 0.f; }
    }
    __syncthreads();

    int ch = tid & 3;              // col group: float4 cols [ch*4, ch*4+4)
    int rp = tid >> 2;             // row pair index 0..63
    int row0 = blockIdx.x * 128 + rp * 2;
    bool v0 = row0 < M;
    bool v1 = (row0 + 1) < M;
    bool dobn = (Sin != nullptr);

    const float4* p0 = In + (size_t)(v0 ? row0 : 0) * 16;
    const float4* p1 = In + (size_t)(v1 ? row0 + 1 : 0) * 16;

    float4 acc0[4], acc1[4];
    const float4* b4 = (const float4*)bias;
#pragma unroll
    for (int c = 0; c < 4; ++c) { acc0[c] = b4[ch * 4 + c]; acc1[c] = acc0[c]; }

#pragma unroll 1
    for (int kc = 0; kc < 4; ++kc) {
        float u0[16], u1[16];
#pragma unroll
        for (int j = 0; j < 4; ++j) {
            float4 h0 = p0[kc * 4 + j];
            float4 h1 = p1[kc * 4 + j];
            int kb = kc * 16 + j * 4;
            if (dobn) {
                u0[j*4+0] = bnr1(As_[kb+0], Bb_[kb+0], h0.x);
                u0[j*4+1] = bnr1(As_[kb+1], Bb_[kb+1], h0.y);
                u0[j*4+2] = bnr1(As_[kb+2], Bb_[kb+2], h0.z);
                u0[j*4+3] = bnr1(As_[kb+3], Bb_[kb+3], h0.w);
                u1[j*4+0] = bnr1(As_[kb+0], Bb_[kb+0], h1.x);
                u1[j*4+1] = bnr1(As_[kb+1], Bb_[kb+1], h1.y);
                u1[j*4+2] = bnr1(As_[kb+2], Bb_[kb+2], h1.z);
                u1[j*4+3] = bnr1(As_[kb+3], Bb_[kb+3], h1.w);
            } else {
                u0[j*4+0] = h0.x; u0[j*4+1] = h0.y; u0[j*4+2] = h0.z; u0[j*4+3] = h0.w;
                u1[j*4+0] = h1.x; u1[j*4+1] = h1.y; u1[j*4+2] = h1.z; u1[j*4+3] = h1.w;
            }
        }
#pragma unroll
        for (int k = 0; k < 16; ++k) {
            int kk = kc * 16 + k;
            float a0 = u0[k], a1 = u1[k];
#pragma unroll
            for (int c = 0; c < 4; ++c) {
                float4 bv = Bs[kk][ch * 4 + c];
                acc0[c].x += a0 * bv.x; acc0[c].y += a0 * bv.y;
                acc0[c].z += a0 * bv.z; acc0[c].w += a0 * bv.w;
                acc1[c].x += a1 * bv.x; acc1[c].y += a1 * bv.y;
                acc1[c].z += a1 * bv.z; acc1[c].w += a1 * bv.w;
            }
        }
    }
    if (v0) {
        float4* o0 = Out + (size_t)row0 * 16 + ch * 4;
#pragma unroll
        for (int c = 0; c < 4; ++c) o0[c] = acc0[c];
    }
    if (v1) {
        float4* o1 = Out + (size_t)(row0 + 1) * 16 + ch * 4;
#pragma unroll
        for (int c = 0; c < 4; ++c) o1[c] = acc1[c];
    }

    // ---- fused column stats (no early return anywhere above) ----
    float4 zero = make_float4(0.f, 0.f, 0.f, 0.f);
    if (!v0) { acc0[0] = zero; acc0[1] = zero; acc0[2] = zero; acc0[3] = zero; }
    if (!v1) { acc1[0] = zero; acc1[1] = zero; acc1[2] = zero; acc1[3] = zero; }
    float4 s4[4], q4[4];
#pragma unroll
    for (int c = 0; c < 4; ++c) {
        s4[c].x = acc0[c].x + acc1[c].x; s4[c].y = acc0[c].y + acc1[c].y;
        s4[c].z = acc0[c].z + acc1[c].z; s4[c].w = acc0[c].w + acc1[c].w;
        q4[c].x = acc0[c].x * acc0[c].x + acc1[c].x * acc1[c].x;
        q4[c].y = acc0[c].y * acc0[c].y + acc1[c].y * acc1[c].y;
        q4[c].z = acc0[c].z * acc0[c].z + acc1[c].z * acc1[c].z;
        q4[c].w = acc0[c].w * acc0[c].w + acc1[c].w * acc1[c].w;
    }
#pragma unroll
    for (int off = 4; off < 64; off <<= 1) {
#pragma unroll
        for (int c = 0; c < 4; ++c) {
            s4[c].x += __shfl_xor(s4[c].x, off); s4[c].y += __shfl_xor(s4[c].y, off);
            s4[c].z += __shfl_xor(s4[c].z, off); s4[c].w += __shfl_xor(s4[c].w, off);
            q4[c].x += __shfl_xor(q4[c].x, off); q4[c].y += __shfl_xor(q4[c].y, off);
            q4[c].z += __shfl_xor(q4[c].z, off); q4[c].w += __shfl_xor(q4[c].w, off);
        }
    }
    int wave = tid >> 6, lane = tid & 63;
    if (lane < 4) {   // lane == ch here
#pragma unroll
        for (int c = 0; c < 4; ++c) {
            int cb = lane * 16 + c * 4;
            SRED[wave][cb + 0] = s4[c].x; SRED[wave][cb + 1] = s4[c].y;
            SRED[wave][cb + 2] = s4[c].z; SRED[wave][cb + 3] = s4[c].w;
            SRED[wave][64 + cb + 0] = q4[c].x; SRED[wave][64 + cb + 1] = q4[c].y;
            SRED[wave][64 + cb + 2] = q4[c].z; SRED[wave][64 + cb + 3] = q4[c].w;
        }
    }
    __syncthreads();
    if (tid < 128) {
        float v = SRED[0][tid] + SRED[1][tid] + SRED[2][tid] + SRED[3][tid];
        unsafeAtomicAdd(&Sout[tid], v);
    }
}

// -------- per-graph mean pool with BN2+ReLU fused on read -------------------
__global__ __launch_bounds__(256) void k_pool(const float4* __restrict__ H,
        const int* __restrict__ batch, const float* __restrict__ Sin,
        const float* __restrict__ g, const float* __restrict__ bt,
        float* __restrict__ POOL, float* __restrict__ CNT,
        int M, int chunk, float invM)
{
    int q = threadIdx.x & 15, rs = threadIdx.x >> 4;
    float as[4], bs[4];
#pragma unroll
    for (int j = 0; j < 4; ++j) {
        int c = q * 4 + j;
        float mu = Sin[c] * invM;
        float var = Sin[64 + c] * invM - mu * mu;
        float a = g[c] * rsqrtf(var + BN_EPS);
        as[j] = a;
        bs[j] = bt[c] - a * mu;
    }
    int start = blockIdx.x * chunk;
    int end = min(M, start + chunk);
    int curg = -1;
    float4 acc = make_float4(0.f, 0.f, 0.f, 0.f);
    float cl = 0.f;
    for (int r = start + rs; r < end; r += 16) {
        int gg = batch[r];
        float4 v = H[(size_t)r * 16 + q];
        v.x = bnr1(as[0], bs[0], v.x); v.y = bnr1(as[1], bs[1], v.y);
        v.z = bnr1(as[2], bs[2], v.z); v.w = bnr1(as[3], bs[3], v.w);
        if (gg != curg) {
            if (curg >= 0) {
                atomicAdd4(POOL + (size_t)curg * 64 + q * 4, acc);
                if (q == 0) unsafeAtomicAdd(CNT + curg, cl);
            }
            curg = gg;
            acc = make_float4(0.f, 0.f, 0.f, 0.f);
            cl = 0.f;
        }
        acc.x += v.x; acc.y += v.y; acc.z += v.z; acc.w += v.w;
        cl += 1.f;
    }
    if (curg >= 0) {
        atomicAdd4(POOL + (size_t)curg * 64 + q * 4, acc);
        if (q == 0) unsafeAtomicAdd(CNT + curg, cl);
    }
}

// -------- head --------------------------------------------------------------
__global__ __launch_bounds__(256) void k_head(const float* __restrict__ POOL,
        const float* __restrict__ CNT, const float* __restrict__ Wh,
        const float* __restrict__ bh, float* __restrict__ OUT, int ngraph)
{
    int lane = threadIdx.x & 63;
    int wv = threadIdx.x >> 6;
    int gidx = blockIdx.x * 4 + wv;
    if (gidx >= ngraph) return;
    float c = fmaxf(CNT[gidx], 1.0f);
    float v = POOL[(size_t)gidx * 64 + lane] / c * Wh[lane];
#pragma unroll
    for (int off = 1; off < 64; off <<= 1) v += __shfl_xor(v, off);
    if (lane == 0) OUT[gidx] = v + bh[0];
}

extern "C" void kernel_launch(void* const* d_in, const int* in_sizes, int n_in,
                              void* d_out, int out_size, void* d_ws, size_t ws_size,
                              hipStream_t stream)
{
    const float* x   = (const float*)d_in[0];
    const int*   ei  = (const int*)d_in[1];
    const int*   bat = (const int*)d_in[2];
    const float* W1  = (const float*)d_in[3];
    const float* b1  = (const float*)d_in[4];
    const float* g1  = (const float*)d_in[5];
    const float* bt1 = (const float*)d_in[6];
    const float* W2  = (const float*)d_in[7];
    const float* b2  = (const float*)d_in[8];
    const float* g2  = (const float*)d_in[9];
    const float* bt2 = (const float*)d_in[10];
    const float* eps = (const float*)d_in[11];
    const float* Wh  = (const float*)d_in[12];
    const float* bh  = (const float*)d_in[13];
    float* out = (float*)d_out;

    int M = in_sizes[0] / 64;
    int nedges = in_sizes[1] / 2;
    const int* src = ei;
    const int* dst = ei + nedges;
    const int NG = 512;
    float invM = 1.0f / (float)M;

    float* ws = (float*)d_ws;
    size_t NE = (size_t)M * 64;
    float* P0   = ws;               // Z ping
    float* P1   = ws + NE;          // Z pong
    float* V    = ws + 2 * NE;
    float* S1   = ws + 3 * NE;      // 4 layers x 128
    float* S2   = S1 + 512;
    float* POOL = S2 + 512;         // 512 x 64
    float* CNT  = POOL + (size_t)NG * 64;  // 512

    int* rowptr = (int*)(CNT + NG);        // M+1
    int* fillp  = rowptr + (M + 1);        // M
    int* deg    = fillp + M;               // M
    int* incl   = deg + M;                 // M
    int* bsum   = incl + M;                // 512
    int* csr    = bsum + 512;              // nedges

    hipMemsetAsync(deg, 0, (size_t)M * sizeof(int), stream);
    hipMemsetAsync(S1, 0, (512 + 512 + (size_t)NG * 64 + NG) * sizeof(float), stream);

    int edgeGrid = (nedges + 255) / 256;

    // ---- CSR build ----
    k_count<<<edgeGrid, 256, 0, stream>>>(dst, deg, nedges);
    int NB = (M + 255) / 256;
    k_scanA<<<NB, 256, 0, stream>>>(deg, incl, bsum, M);
    k_scanB<<<1, 512, 0, stream>>>(bsum, NB);
    k_scanC<<<NB, 256, 0, stream>>>(deg, incl, bsum, rowptr, fillp, M);
    k_fill<<<1024, 256, 0, stream>>>(src, dst, fillp, csr, nedges, M);

    int gemmGrid = (M + 127) / 128;

    const float* prevZ = x;
    for (int i = 0; i < 4; ++i) {
        float* Zb = (i & 1) ? P1 : P0;
        const float* Sprev = (i == 0) ? nullptr : (S2 + (size_t)(i - 1) * 128);
        const float* gprev = (i == 0) ? g2 : (g2 + (size_t)(i - 1) * 64);
        const float* bprev = (i == 0) ? bt2 : (bt2 + (size_t)(i - 1) * 64);

        k_fused<<<1024, 256, 0, stream>>>((const float4*)prevZ, rowptr, csr,
                Sprev, gprev, bprev, eps, i, W1 + (size_t)i * 4096, b1 + i * 64,
                V, S1 + (size_t)i * 128, M, invM);
        k_gemm<<<gemmGrid, 256, 0, stream>>>((const float4*)V, S1 + (size_t)i * 128,
                g1 + i * 64, bt1 + i * 64, W2 + (size_t)i * 4096, b2 + i * 64,
                (float4*)Zb, S2 + (size_t)i * 128, M);
        prevZ = Zb;
    }
    int chunk = (M + 511) / 512;
    k_pool<<<512, 256, 0, stream>>>((const float4*)prevZ, bat, S2 + 3 * 128,
            g2 + 192, bt2 + 192, POOL, CNT, M, chunk, invM);
    k_head<<<(NG + 3) / 4, 256, 0, stream>>>(POOL, CNT, Wh, bh, out, NG);
}

// Round 8
// 675.787 us; speedup vs baseline: 1.2914x; 1.2914x over previous
//
#include <hip/hip_runtime.h>

#define BN_EPS 1e-5f

typedef unsigned int  uint_t;
typedef unsigned short ushort_t;

__device__ __forceinline__ void atomicAdd4(float* p, float4 v) {
    unsafeAtomicAdd(p + 0, v.x);
    unsafeAtomicAdd(p + 1, v.y);
    unsafeAtomicAdd(p + 2, v.z);
    unsafeAtomicAdd(p + 3, v.w);
}

__device__ __forceinline__ float bnr1(float a, float b, float v) {
    return fmaxf(fmaf(a, v, b), 0.0f);
}

// ---- bf16 helpers (RNE pack, exact unpack) --------------------------------
__device__ __forceinline__ ushort_t f2bf(float f) {
    uint_t x = __float_as_uint(f);
    uint_t r = x + 0x7fffu + ((x >> 16) & 1u);
    return (ushort_t)(r >> 16);
}
__device__ __forceinline__ uint_t pack2(float a, float b) {
    return ((uint_t)f2bf(b) << 16) | (uint_t)f2bf(a);
}
__device__ __forceinline__ float lo2f(uint_t p) { return __uint_as_float(p << 16); }
__device__ __forceinline__ float hi2f(uint_t p) { return __uint_as_float(p & 0xffff0000u); }

// ===================== fp32 -> bf16 cast of x (once) ========================
__global__ __launch_bounds__(256) void k_cast(const float4* __restrict__ X,
        uint2* __restrict__ Xb, int n4)
{
    for (int i = blockIdx.x * 256 + threadIdx.x; i < n4; i += gridDim.x * 256) {
        float4 v = X[i];
        uint2 o;
        o.x = pack2(v.x, v.y);
        o.y = pack2(v.z, v.w);
        Xb[i] = o;
    }
}

// ===================== CSR build (once, reused for all 4 layers) ============

__global__ __launch_bounds__(256) void k_count(const int* __restrict__ dst,
        int* __restrict__ deg, int nedges)
{
    int e = blockIdx.x * 256 + threadIdx.x;
    if (e < nedges) atomicAdd(&deg[dst[e]], 1);
}

__global__ __launch_bounds__(256) void k_scanA(const int* __restrict__ deg,
        int* __restrict__ incl, int* __restrict__ bsum, int N)
{
    __shared__ int tmp[256];
    int i = blockIdx.x * 256 + threadIdx.x;
    int d = (i < N) ? deg[i] : 0;
    tmp[threadIdx.x] = d;
    __syncthreads();
    for (int off = 1; off < 256; off <<= 1) {
        int val = (threadIdx.x >= off) ? tmp[threadIdx.x - off] : 0;
        __syncthreads();
        tmp[threadIdx.x] += val;
        __syncthreads();
    }
    if (i < N) incl[i] = tmp[threadIdx.x];
    if (threadIdx.x == 255) bsum[blockIdx.x] = tmp[255];
}

__global__ __launch_bounds__(512) void k_scanB(int* __restrict__ bsum, int NB)
{
    __shared__ int tmp[512];
    int tid = threadIdx.x;
    int d = (tid < NB) ? bsum[tid] : 0;
    tmp[tid] = d;
    __syncthreads();
    for (int off = 1; off < 512; off <<= 1) {
        int val = (tid >= off) ? tmp[tid - off] : 0;
        __syncthreads();
        tmp[tid] += val;
        __syncthreads();
    }
    if (tid < NB) bsum[tid] = tmp[tid] - d;   // exclusive
}

__global__ __launch_bounds__(256) void k_scanC(const int* __restrict__ deg,
        const int* __restrict__ incl, const int* __restrict__ bsum,
        int* __restrict__ rowptr, int* __restrict__ fill, int N)
{
    int i = blockIdx.x * 256 + threadIdx.x;
    if (i >= N) return;
    int d = deg[i];
    int excl = incl[i] - d + bsum[blockIdx.x];
    rowptr[i] = excl;
    fill[i] = excl;
    if (i == N - 1) rowptr[N] = excl + d;
}

// XCD-partitioned fill (R6 win: csr lines dirtied by one XCD slot each)
__global__ __launch_bounds__(256) void k_fill(const int* __restrict__ src,
        const int* __restrict__ dst, int* __restrict__ fillp,
        int* __restrict__ csr, int nedges, int M)
{
    int nx = gridDim.x >> 3;
    int x  = blockIdx.x & 7;
    int ci = blockIdx.x >> 3;
    int lo = (int)(((long long)M * x) >> 3);
    int hi = (int)(((long long)M * (x + 1)) >> 3);
    int chunk = (nedges + nx - 1) / nx;
    int e0 = ci * chunk;
    int e1 = min(nedges, e0 + chunk);
    for (int e = e0 + threadIdx.x; e < e1; e += 256) {
        int d = dst[e];
        if (d >= lo && d < hi) {
            int pos = atomicAdd(&fillp[d], 1);
            csr[pos] = src[e];
        }
    }
}

// ===================== gather (bf16 in/out): BN2(prev)+ReLU fused ===========
// U[d] = (1+eps)*val(d) + sum_{s in adj(d)} val(s); val = relu(a*Z+b) or raw.
// wave = 1 node; lane = (sub 0..3, quad 0..15); uint2 = 4 bf16 per lane.
// All control flow around shfls is wave-uniform (R3 lesson).
__global__ __launch_bounds__(256) void k_gather(const uint2* __restrict__ H,
        const int* __restrict__ rowptr, const int* __restrict__ csr,
        const float* __restrict__ Sin, const float* __restrict__ g,
        const float* __restrict__ bt, const float* __restrict__ epsp,
        int layer, uint2* __restrict__ U, int N, float invM)
{
    int lane = threadIdx.x & 63;
    int wv = threadIdx.x >> 6;
    int node = blockIdx.x * 4 + wv;
    if (node >= N) return;
    int q = lane & 15, sub = lane >> 4;

    float4 A4 = make_float4(1.f, 1.f, 1.f, 1.f);
    float4 B4 = make_float4(0.f, 0.f, 0.f, 0.f);
    bool dobn = (Sin != nullptr);
    if (dobn) {
        float as[4], bs[4];
#pragma unroll
        for (int j = 0; j < 4; ++j) {
            int c = q * 4 + j;
            float mu = Sin[c] * invM;
            float var = Sin[64 + c] * invM - mu * mu;
            float a = g[c] * rsqrtf(var + BN_EPS);
            as[j] = a;
            bs[j] = bt[c] - a * mu;
        }
        A4 = make_float4(as[0], as[1], as[2], as[3]);
        B4 = make_float4(bs[0], bs[1], bs[2], bs[3]);
    }

    int start = rowptr[node], end = rowptr[node + 1];
    float4 acc = make_float4(0.f, 0.f, 0.f, 0.f);

    for (int base = start; base < end; base += 64) {
        int n = min(64, end - base);               // wave-uniform
        int myidx = (lane < n) ? csr[base + lane] : 0;
        int nIter = (n + 15) >> 4;                 // wave-uniform
        for (int t = 0; t < nIter; ++t) {
            int j0 = t * 16 + sub;
            int j1 = j0 + 4, j2 = j0 + 8, j3 = j0 + 12;
            int s0 = __shfl(myidx, (j0 < n) ? j0 : 0);
            int s1 = __shfl(myidx, (j1 < n) ? j1 : 0);
            int s2 = __shfl(myidx, (j2 < n) ? j2 : 0);
            int s3 = __shfl(myidx, (j3 < n) ? j3 : 0);
            uint2 r0 = H[(size_t)s0 * 16 + q];
            uint2 r1 = H[(size_t)s1 * 16 + q];
            uint2 r2 = H[(size_t)s2 * 16 + q];
            uint2 r3 = H[(size_t)s3 * 16 + q];
            float4 v0 = make_float4(lo2f(r0.x), hi2f(r0.x), lo2f(r0.y), hi2f(r0.y));
            float4 v1 = make_float4(lo2f(r1.x), hi2f(r1.x), lo2f(r1.y), hi2f(r1.y));
            float4 v2 = make_float4(lo2f(r2.x), hi2f(r2.x), lo2f(r2.y), hi2f(r2.y));
            float4 v3 = make_float4(lo2f(r3.x), hi2f(r3.x), lo2f(r3.y), hi2f(r3.y));
            if (dobn) {
                v0.x = bnr1(A4.x, B4.x, v0.x); v0.y = bnr1(A4.y, B4.y, v0.y);
                v0.z = bnr1(A4.z, B4.z, v0.z); v0.w = bnr1(A4.w, B4.w, v0.w);
                v1.x = bnr1(A4.x, B4.x, v1.x); v1.y = bnr1(A4.y, B4.y, v1.y);
                v1.z = bnr1(A4.z, B4.z, v1.z); v1.w = bnr1(A4.w, B4.w, v1.w);
                v2.x = bnr1(A4.x, B4.x, v2.x); v2.y = bnr1(A4.y, B4.y, v2.y);
                v2.z = bnr1(A4.z, B4.z, v2.z); v2.w = bnr1(A4.w, B4.w, v2.w);
                v3.x = bnr1(A4.x, B4.x, v3.x); v3.y = bnr1(A4.y, B4.y, v3.y);
                v3.z = bnr1(A4.z, B4.z, v3.z); v3.w = bnr1(A4.w, B4.w, v3.w);
            }
            if (j0 < n) { acc.x += v0.x; acc.y += v0.y; acc.z += v0.z; acc.w += v0.w; }
            if (j1 < n) { acc.x += v1.x; acc.y += v1.y; acc.z += v1.z; acc.w += v1.w; }
            if (j2 < n) { acc.x += v2.x; acc.y += v2.y; acc.z += v2.z; acc.w += v2.w; }
            if (j3 < n) { acc.x += v3.x; acc.y += v3.y; acc.z += v3.z; acc.w += v3.w; }
        }
    }
    acc.x += __shfl_xor(acc.x, 16); acc.y += __shfl_xor(acc.y, 16);
    acc.z += __shfl_xor(acc.z, 16); acc.w += __shfl_xor(acc.w, 16);
    acc.x += __shfl_xor(acc.x, 32); acc.y += __shfl_xor(acc.y, 32);
    acc.z += __shfl_xor(acc.z, 32); acc.w += __shfl_xor(acc.w, 32);

    if (sub == 0) {
        uint2 hr = H[(size_t)node * 16 + q];
        float4 hv = make_float4(lo2f(hr.x), hi2f(hr.x), lo2f(hr.y), hi2f(hr.y));
        if (dobn) {
            hv.x = bnr1(A4.x, B4.x, hv.x); hv.y = bnr1(A4.y, B4.y, hv.y);
            hv.z = bnr1(A4.z, B4.z, hv.z); hv.w = bnr1(A4.w, B4.w, hv.w);
        }
        float e = 1.0f + epsp[layer];
        float4 o;
        o.x = fmaf(e, hv.x, acc.x); o.y = fmaf(e, hv.y, acc.y);
        o.z = fmaf(e, hv.z, acc.z); o.w = fmaf(e, hv.w, acc.w);
        uint2 ou;
        ou.x = pack2(o.x, o.y);
        ou.y = pack2(o.z, o.w);
        U[(size_t)node * 16 + q] = ou;
    }
}

// ===================== GEMM (bf16 in/out) + fused column stats ==============
// Out[r][c] = sum_k f(In[r][k]) * W[k][c] + bias[c],  f = relu(a*v+b) or id
// Stats are computed on the ROUNDED (stored) values for BN self-consistency.
// 2 rows x 16 cols per thread; no early return (all threads reach shuffles);
// kc loop not unrolled (R4 lesson: full unroll -> 256 VGPR + spill).
__global__ __launch_bounds__(256) void k_gemm(const uint4* __restrict__ In,
        const float* __restrict__ Sin, const float* __restrict__ g,
        const float* __restrict__ bt, const float* __restrict__ W,
        const float* __restrict__ bias, uint4* __restrict__ Out,
        float* __restrict__ Sout, int M)
{
    __shared__ float4 Bs[64][16];   // W tile (fp32), 16 KB
    __shared__ float As_[64];
    __shared__ float Bb_[64];
    __shared__ float SRED[4][128];
    int tid = threadIdx.x;
    const float4* W4 = (const float4*)W;
#pragma unroll
    for (int i = 0; i < 4; ++i)
        ((float4*)Bs)[tid + 256 * i] = W4[tid + 256 * i];
    if (tid < 64) {
        if (Sin) {
            float invM = 1.0f / (float)M;
            float mu = Sin[tid] * invM;
            float var = Sin[64 + tid] * invM - mu * mu;
            float a = g[tid] * rsqrtf(var + BN_EPS);
            As_[tid] = a;
            Bb_[tid] = bt[tid] - a * mu;
        } else { As_[tid] = 1.f; Bb_[tid] = 0.f; }
    }
    __syncthreads();

    int ch = tid & 3;              // col group: float cols [ch*16, ch*16+16)
    int rp = tid >> 2;             // row pair index 0..63
    int row0 = blockIdx.x * 128 + rp * 2;
    bool v0 = row0 < M;
    bool v1 = (row0 + 1) < M;
    bool dobn = (Sin != nullptr);

    size_t pb0 = (size_t)(v0 ? row0 : 0) * 8;        // row stride = 8 uint4
    size_t pb1 = (size_t)(v1 ? row0 + 1 : 0) * 8;

    float4 acc0[4], acc1[4];
    const float4* b4 = (const float4*)bias;
#pragma unroll
    for (int c = 0; c < 4; ++c) { acc0[c] = b4[ch * 4 + c]; acc1[c] = acc0[c]; }

#pragma unroll 1
    for (int kc = 0; kc < 4; ++kc) {
        uint4 A0 = In[pb0 + kc * 2], B0 = In[pb0 + kc * 2 + 1];
        uint4 A1 = In[pb1 + kc * 2], B1 = In[pb1 + kc * 2 + 1];
        float u0[16], u1[16];
        u0[0]=lo2f(A0.x); u0[1]=hi2f(A0.x); u0[2]=lo2f(A0.y); u0[3]=hi2f(A0.y);
        u0[4]=lo2f(A0.z); u0[5]=hi2f(A0.z); u0[6]=lo2f(A0.w); u0[7]=hi2f(A0.w);
        u0[8]=lo2f(B0.x); u0[9]=hi2f(B0.x); u0[10]=lo2f(B0.y); u0[11]=hi2f(B0.y);
        u0[12]=lo2f(B0.z); u0[13]=hi2f(B0.z); u0[14]=lo2f(B0.w); u0[15]=hi2f(B0.w);
        u1[0]=lo2f(A1.x); u1[1]=hi2f(A1.x); u1[2]=lo2f(A1.y); u1[3]=hi2f(A1.y);
        u1[4]=lo2f(A1.z); u1[5]=hi2f(A1.z); u1[6]=lo2f(A1.w); u1[7]=hi2f(A1.w);
        u1[8]=lo2f(B1.x); u1[9]=hi2f(B1.x); u1[10]=lo2f(B1.y); u1[11]=hi2f(B1.y);
        u1[12]=lo2f(B1.z); u1[13]=hi2f(B1.z); u1[14]=lo2f(B1.w); u1[15]=hi2f(B1.w);
        if (dobn) {
#pragma unroll
            for (int t = 0; t < 16; ++t) {
                int kb = kc * 16 + t;
                u0[t] = bnr1(As_[kb], Bb_[kb], u0[t]);
                u1[t] = bnr1(As_[kb], Bb_[kb], u1[t]);
            }
        }
#pragma unroll
        for (int k = 0; k < 16; ++k) {
            int kk = kc * 16 + k;
            float a0 = u0[k], a1 = u1[k];
#pragma unroll
            for (int c = 0; c < 4; ++c) {
                float4 bv = Bs[kk][ch * 4 + c];
                acc0[c].x += a0 * bv.x; acc0[c].y += a0 * bv.y;
                acc0[c].z += a0 * bv.z; acc0[c].w += a0 * bv.w;
                acc1[c].x += a1 * bv.x; acc1[c].y += a1 * bv.y;
                acc1[c].z += a1 * bv.z; acc1[c].w += a1 * bv.w;
            }
        }
    }

    // pack (RNE) + store + rounded values for stats
    float4 r0[4], r1[4];
    uint_t pk0[8], pk1[8];
#pragma unroll
    for (int c = 0; c < 4; ++c) {
        pk0[c*2]   = pack2(acc0[c].x, acc0[c].y);
        pk0[c*2+1] = pack2(acc0[c].z, acc0[c].w);
        pk1[c*2]   = pack2(acc1[c].x, acc1[c].y);
        pk1[c*2+1] = pack2(acc1[c].z, acc1[c].w);
        r0[c] = make_float4(lo2f(pk0[c*2]), hi2f(pk0[c*2]), lo2f(pk0[c*2+1]), hi2f(pk0[c*2+1]));
        r1[c] = make_float4(lo2f(pk1[c*2]), hi2f(pk1[c*2]), lo2f(pk1[c*2+1]), hi2f(pk1[c*2+1]));
    }
    if (v0) {
        uint4 oa = make_uint4(pk0[0], pk0[1], pk0[2], pk0[3]);
        uint4 ob = make_uint4(pk0[4], pk0[5], pk0[6], pk0[7]);
        Out[(size_t)row0 * 8 + ch * 2] = oa;
        Out[(size_t)row0 * 8 + ch * 2 + 1] = ob;
    }
    if (v1) {
        uint4 oa = make_uint4(pk1[0], pk1[1], pk1[2], pk1[3]);
        uint4 ob = make_uint4(pk1[4], pk1[5], pk1[6], pk1[7]);
        Out[(size_t)(row0 + 1) * 8 + ch * 2] = oa;
        Out[(size_t)(row0 + 1) * 8 + ch * 2 + 1] = ob;
    }

    // ---- fused column stats on rounded values ----
    float4 zero = make_float4(0.f, 0.f, 0.f, 0.f);
    if (!v0) { r0[0] = zero; r0[1] = zero; r0[2] = zero; r0[3] = zero; }
    if (!v1) { r1[0] = zero; r1[1] = zero; r1[2] = zero; r1[3] = zero; }
    float4 s4[4], q4[4];
#pragma unroll
    for (int c = 0; c < 4; ++c) {
        s4[c].x = r0[c].x + r1[c].x; s4[c].y = r0[c].y + r1[c].y;
        s4[c].z = r0[c].z + r1[c].z; s4[c].w = r0[c].w + r1[c].w;
        q4[c].x = r0[c].x * r0[c].x + r1[c].x * r1[c].x;
        q4[c].y = r0[c].y * r0[c].y + r1[c].y * r1[c].y;
        q4[c].z = r0[c].z * r0[c].z + r1[c].z * r1[c].z;
        q4[c].w = r0[c].w * r0[c].w + r1[c].w * r1[c].w;
    }
#pragma unroll
    for (int off = 4; off < 64; off <<= 1) {
#pragma unroll
        for (int c = 0; c < 4; ++c) {
            s4[c].x += __shfl_xor(s4[c].x, off); s4[c].y += __shfl_xor(s4[c].y, off);
            s4[c].z += __shfl_xor(s4[c].z, off); s4[c].w += __shfl_xor(s4[c].w, off);
            q4[c].x += __shfl_xor(q4[c].x, off); q4[c].y += __shfl_xor(q4[c].y, off);
            q4[c].z += __shfl_xor(q4[c].z, off); q4[c].w += __shfl_xor(q4[c].w, off);
        }
    }
    int wave = tid >> 6, lane = tid & 63;
    if (lane < 4) {   // lane == ch here
#pragma unroll
        for (int c = 0; c < 4; ++c) {
            int cb = lane * 16 + c * 4;
            SRED[wave][cb + 0] = s4[c].x; SRED[wave][cb + 1] = s4[c].y;
            SRED[wave][cb + 2] = s4[c].z; SRED[wave][cb + 3] = s4[c].w;
            SRED[wave][64 + cb + 0] = q4[c].x; SRED[wave][64 + cb + 1] = q4[c].y;
            SRED[wave][64 + cb + 2] = q4[c].z; SRED[wave][64 + cb + 3] = q4[c].w;
        }
    }
    __syncthreads();
    if (tid < 128) {
        float v = SRED[0][tid] + SRED[1][tid] + SRED[2][tid] + SRED[3][tid];
        unsafeAtomicAdd(&Sout[tid], v);
    }
}

// -------- per-graph mean pool (bf16 in) with BN2+ReLU fused on read ---------
__global__ __launch_bounds__(256) void k_pool(const uint2* __restrict__ H,
        const int* __restrict__ batch, const float* __restrict__ Sin,
        const float* __restrict__ g, const float* __restrict__ bt,
        float* __restrict__ POOL, float* __restrict__ CNT,
        int M, int chunk, float invM)
{
    int q = threadIdx.x & 15, rs = threadIdx.x >> 4;
    float as[4], bs[4];
#pragma unroll
    for (int j = 0; j < 4; ++j) {
        int c = q * 4 + j;
        float mu = Sin[c] * invM;
        float var = Sin[64 + c] * invM - mu * mu;
        float a = g[c] * rsqrtf(var + BN_EPS);
        as[j] = a;
        bs[j] = bt[c] - a * mu;
    }
    int start = blockIdx.x * chunk;
    int end = min(M, start + chunk);
    int curg = -1;
    float4 acc = make_float4(0.f, 0.f, 0.f, 0.f);
    float cl = 0.f;
    for (int r = start + rs; r < end; r += 16) {
        int gg = batch[r];
        uint2 hr = H[(size_t)r * 16 + q];
        float4 v = make_float4(lo2f(hr.x), hi2f(hr.x), lo2f(hr.y), hi2f(hr.y));
        v.x = bnr1(as[0], bs[0], v.x); v.y = bnr1(as[1], bs[1], v.y);
        v.z = bnr1(as[2], bs[2], v.z); v.w = bnr1(as[3], bs[3], v.w);
        if (gg != curg) {
            if (curg >= 0) {
                atomicAdd4(POOL + (size_t)curg * 64 + q * 4, acc);
                if (q == 0) unsafeAtomicAdd(CNT + curg, cl);
            }
            curg = gg;
            acc = make_float4(0.f, 0.f, 0.f, 0.f);
            cl = 0.f;
        }
        acc.x += v.x; acc.y += v.y; acc.z += v.z; acc.w += v.w;
        cl += 1.f;
    }
    if (curg >= 0) {
        atomicAdd4(POOL + (size_t)curg * 64 + q * 4, acc);
        if (q == 0) unsafeAtomicAdd(CNT + curg, cl);
    }
}

// -------- head --------------------------------------------------------------
__global__ __launch_bounds__(256) void k_head(const float* __restrict__ POOL,
        const float* __restrict__ CNT, const float* __restrict__ Wh,
        const float* __restrict__ bh, float* __restrict__ OUT, int ngraph)
{
    int lane = threadIdx.x & 63;
    int wv = threadIdx.x >> 6;
    int gidx = blockIdx.x * 4 + wv;
    if (gidx >= ngraph) return;
    float c = fmaxf(CNT[gidx], 1.0f);
    float v = POOL[(size_t)gidx * 64 + lane] / c * Wh[lane];
#pragma unroll
    for (int off = 1; off < 64; off <<= 1) v += __shfl_xor(v, off);
    if (lane == 0) OUT[gidx] = v + bh[0];
}

extern "C" void kernel_launch(void* const* d_in, const int* in_sizes, int n_in,
                              void* d_out, int out_size, void* d_ws, size_t ws_size,
                              hipStream_t stream)
{
    const float* x   = (const float*)d_in[0];
    const int*   ei  = (const int*)d_in[1];
    const int*   bat = (const int*)d_in[2];
    const float* W1  = (const float*)d_in[3];
    const float* b1  = (const float*)d_in[4];
    const float* g1  = (const float*)d_in[5];
    const float* bt1 = (const float*)d_in[6];
    const float* W2  = (const float*)d_in[7];
    const float* b2  = (const float*)d_in[8];
    const float* g2  = (const float*)d_in[9];
    const float* bt2 = (const float*)d_in[10];
    const float* eps = (const float*)d_in[11];
    const float* Wh  = (const float*)d_in[12];
    const float* bh  = (const float*)d_in[13];
    float* out = (float*)d_out;

    int M = in_sizes[0] / 64;
    int nedges = in_sizes[1] / 2;
    const int* src = ei;
    const int* dst = ei + nedges;
    const int NG = 512;
    float invM = 1.0f / (float)M;

    size_t NE = (size_t)M * 64;      // elements per feature array
    ushort_t* Xb  = (ushort_t*)d_ws;   // NE bf16
    ushort_t* P0b = Xb + NE;           // NE bf16 (U/Z ping)
    ushort_t* P1b = P0b + NE;          // NE bf16 (U/Z pong)
    ushort_t* Vb  = P1b + NE;          // NE bf16
    float* S1   = (float*)(Vb + NE);   // 4 layers x 128
    float* S2   = S1 + 512;
    float* POOL = S2 + 512;            // 512 x 64
    float* CNT  = POOL + (size_t)NG * 64;  // 512

    int* rowptr = (int*)(CNT + NG);        // M+1
    int* fillp  = rowptr + (M + 1);        // M
    int* deg    = fillp + M;               // M
    int* incl   = deg + M;                 // M
    int* bsum   = incl + M;                // 512
    int* csr    = bsum + 512;              // nedges

    hipMemsetAsync(deg, 0, (size_t)M * sizeof(int), stream);
    hipMemsetAsync(S1, 0, (512 + 512 + (size_t)NG * 64 + NG) * sizeof(float), stream);

    int edgeGrid = (nedges + 255) / 256;

    // ---- cast x to bf16 (once) ----
    k_cast<<<2048, 256, 0, stream>>>((const float4*)x, (uint2*)Xb, M * 16);

    // ---- CSR build ----
    k_count<<<edgeGrid, 256, 0, stream>>>(dst, deg, nedges);
    int NB = (M + 255) / 256;
    k_scanA<<<NB, 256, 0, stream>>>(deg, incl, bsum, M);
    k_scanB<<<1, 512, 0, stream>>>(bsum, NB);
    k_scanC<<<NB, 256, 0, stream>>>(deg, incl, bsum, rowptr, fillp, M);
    k_fill<<<1024, 256, 0, stream>>>(src, dst, fillp, csr, nedges, M);

    int gemmGrid = (M + 127) / 128;
    int gatherGrid = (M + 3) / 4;

    const ushort_t* prevZ = Xb;
    for (int i = 0; i < 4; ++i) {
        ushort_t* Ub = (i & 1) ? P1b : P0b;
        const float* Sprev = (i == 0) ? nullptr : (S2 + (size_t)(i - 1) * 128);
        const float* gprev = (i == 0) ? g2 : (g2 + (size_t)(i - 1) * 64);
        const float* bprev = (i == 0) ? bt2 : (bt2 + (size_t)(i - 1) * 64);

        k_gather<<<gatherGrid, 256, 0, stream>>>((const uint2*)prevZ, rowptr, csr,
                Sprev, gprev, bprev, eps, i, (uint2*)Ub, M, invM);
        k_gemm<<<gemmGrid, 256, 0, stream>>>((const uint4*)Ub, nullptr, g1, bt1,
                W1 + (size_t)i * 4096, b1 + i * 64, (uint4*)Vb,
                S1 + (size_t)i * 128, M);
        k_gemm<<<gemmGrid, 256, 0, stream>>>((const uint4*)Vb, S1 + (size_t)i * 128,
                g1 + i * 64, bt1 + i * 64, W2 + (size_t)i * 4096, b2 + i * 64,
                (uint4*)Ub, S2 + (size_t)i * 128, M);   // Z overwrites U (dead)
        prevZ = Ub;
    }
    int chunk = (M + 511) / 512;
    k_pool<<<512, 256, 0, stream>>>((const uint2*)prevZ, bat, S2 + 3 * 128,
            g2 + 192, bt2 + 192, POOL, CNT, M, chunk, invM);
    k_head<<<(NG + 3) / 4, 256, 0, stream>>>(POOL, CNT, Wh, bh, out, NG);
}

// Round 9
// 597.337 us; speedup vs baseline: 1.4610x; 1.1313x over previous
//
#include <hip/hip_runtime.h>

#define BN_EPS 1e-5f

typedef unsigned int  uint_t;
typedef unsigned short ushort_t;
typedef __attribute__((ext_vector_type(8))) short short8;
typedef __attribute__((ext_vector_type(4))) float f32x4;

__device__ __forceinline__ void atomicAdd4(float* p, float4 v) {
    unsafeAtomicAdd(p + 0, v.x);
    unsafeAtomicAdd(p + 1, v.y);
    unsafeAtomicAdd(p + 2, v.z);
    unsafeAtomicAdd(p + 3, v.w);
}

__device__ __forceinline__ float bnr1(float a, float b, float v) {
    return fmaxf(fmaf(a, v, b), 0.0f);
}

// ---- bf16 helpers (RNE pack, exact unpack) --------------------------------
__device__ __forceinline__ ushort_t f2bf(float f) {
    uint_t x = __float_as_uint(f);
    uint_t r = x + 0x7fffu + ((x >> 16) & 1u);
    return (ushort_t)(r >> 16);
}
__device__ __forceinline__ uint_t pack2(float a, float b) {
    return ((uint_t)f2bf(b) << 16) | (uint_t)f2bf(a);
}
__device__ __forceinline__ float lo2f(uint_t p) { return __uint_as_float(p << 16); }
__device__ __forceinline__ float hi2f(uint_t p) { return __uint_as_float(p & 0xffff0000u); }
__device__ __forceinline__ float bf2f(ushort_t h) { return __uint_as_float((uint_t)h << 16); }

// ===================== fp32 -> bf16 cast of x (once) ========================
__global__ __launch_bounds__(256) void k_cast(const float4* __restrict__ X,
        uint2* __restrict__ Xb, int n4)
{
    for (int i = blockIdx.x * 256 + threadIdx.x; i < n4; i += gridDim.x * 256) {
        float4 v = X[i];
        uint2 o;
        o.x = pack2(v.x, v.y);
        o.y = pack2(v.z, v.w);
        Xb[i] = o;
    }
}

// ===================== CSR build (once, reused for all 4 layers) ============

__global__ __launch_bounds__(256) void k_count(const int* __restrict__ dst,
        int* __restrict__ deg, int nedges)
{
    int e = blockIdx.x * 256 + threadIdx.x;
    if (e < nedges) atomicAdd(&deg[dst[e]], 1);
}

__global__ __launch_bounds__(256) void k_scanA(const int* __restrict__ deg,
        int* __restrict__ incl, int* __restrict__ bsum, int N)
{
    __shared__ int tmp[256];
    int i = blockIdx.x * 256 + threadIdx.x;
    int d = (i < N) ? deg[i] : 0;
    tmp[threadIdx.x] = d;
    __syncthreads();
    for (int off = 1; off < 256; off <<= 1) {
        int val = (threadIdx.x >= off) ? tmp[threadIdx.x - off] : 0;
        __syncthreads();
        tmp[threadIdx.x] += val;
        __syncthreads();
    }
    if (i < N) incl[i] = tmp[threadIdx.x];
    if (threadIdx.x == 255) bsum[blockIdx.x] = tmp[255];
}

__global__ __launch_bounds__(512) void k_scanB(int* __restrict__ bsum, int NB)
{
    __shared__ int tmp[512];
    int tid = threadIdx.x;
    int d = (tid < NB) ? bsum[tid] : 0;
    tmp[tid] = d;
    __syncthreads();
    for (int off = 1; off < 512; off <<= 1) {
        int val = (tid >= off) ? tmp[tid - off] : 0;
        __syncthreads();
        tmp[tid] += val;
        __syncthreads();
    }
    if (tid < NB) bsum[tid] = tmp[tid] - d;   // exclusive
}

__global__ __launch_bounds__(256) void k_scanC(const int* __restrict__ deg,
        const int* __restrict__ incl, const int* __restrict__ bsum,
        int* __restrict__ rowptr, int* __restrict__ fill, int N)
{
    int i = blockIdx.x * 256 + threadIdx.x;
    if (i >= N) return;
    int d = deg[i];
    int excl = incl[i] - d + bsum[blockIdx.x];
    rowptr[i] = excl;
    fill[i] = excl;
    if (i == N - 1) rowptr[N] = excl + d;
}

// XCD-partitioned fill (R6 win: csr lines dirtied by one XCD slot each)
__global__ __launch_bounds__(256) void k_fill(const int* __restrict__ src,
        const int* __restrict__ dst, int* __restrict__ fillp,
        int* __restrict__ csr, int nedges, int M)
{
    int nx = gridDim.x >> 3;
    int x  = blockIdx.x & 7;
    int ci = blockIdx.x >> 3;
    int lo = (int)(((long long)M * x) >> 3);
    int hi = (int)(((long long)M * (x + 1)) >> 3);
    int chunk = (nedges + nx - 1) / nx;
    int e0 = ci * chunk;
    int e1 = min(nedges, e0 + chunk);
    for (int e = e0 + threadIdx.x; e < e1; e += 256) {
        int d = dst[e];
        if (d >= lo && d < hi) {
            int pos = atomicAdd(&fillp[d], 1);
            csr[pos] = src[e];
        }
    }
}

// ===================== gather (bf16 in/out): BN2(prev)+ReLU fused ===========
// (unchanged from R8 passing version)
__global__ __launch_bounds__(256) void k_gather(const uint2* __restrict__ H,
        const int* __restrict__ rowptr, const int* __restrict__ csr,
        const float* __restrict__ Sin, const float* __restrict__ g,
        const float* __restrict__ bt, const float* __restrict__ epsp,
        int layer, uint2* __restrict__ U, int N, float invM)
{
    int lane = threadIdx.x & 63;
    int wv = threadIdx.x >> 6;
    int node = blockIdx.x * 4 + wv;
    if (node >= N) return;
    int q = lane & 15, sub = lane >> 4;

    float4 A4 = make_float4(1.f, 1.f, 1.f, 1.f);
    float4 B4 = make_float4(0.f, 0.f, 0.f, 0.f);
    bool dobn = (Sin != nullptr);
    if (dobn) {
        float as[4], bs[4];
#pragma unroll
        for (int j = 0; j < 4; ++j) {
            int c = q * 4 + j;
            float mu = Sin[c] * invM;
            float var = Sin[64 + c] * invM - mu * mu;
            float a = g[c] * rsqrtf(var + BN_EPS);
            as[j] = a;
            bs[j] = bt[c] - a * mu;
        }
        A4 = make_float4(as[0], as[1], as[2], as[3]);
        B4 = make_float4(bs[0], bs[1], bs[2], bs[3]);
    }

    int start = rowptr[node], end = rowptr[node + 1];
    float4 acc = make_float4(0.f, 0.f, 0.f, 0.f);

    for (int base = start; base < end; base += 64) {
        int n = min(64, end - base);               // wave-uniform
        int myidx = (lane < n) ? csr[base + lane] : 0;
        int nIter = (n + 15) >> 4;                 // wave-uniform
        for (int t = 0; t < nIter; ++t) {
            int j0 = t * 16 + sub;
            int j1 = j0 + 4, j2 = j0 + 8, j3 = j0 + 12;
            int s0 = __shfl(myidx, (j0 < n) ? j0 : 0);
            int s1 = __shfl(myidx, (j1 < n) ? j1 : 0);
            int s2 = __shfl(myidx, (j2 < n) ? j2 : 0);
            int s3 = __shfl(myidx, (j3 < n) ? j3 : 0);
            uint2 r0 = H[(size_t)s0 * 16 + q];
            uint2 r1 = H[(size_t)s1 * 16 + q];
            uint2 r2 = H[(size_t)s2 * 16 + q];
            uint2 r3 = H[(size_t)s3 * 16 + q];
            float4 v0 = make_float4(lo2f(r0.x), hi2f(r0.x), lo2f(r0.y), hi2f(r0.y));
            float4 v1 = make_float4(lo2f(r1.x), hi2f(r1.x), lo2f(r1.y), hi2f(r1.y));
            float4 v2 = make_float4(lo2f(r2.x), hi2f(r2.x), lo2f(r2.y), hi2f(r2.y));
            float4 v3 = make_float4(lo2f(r3.x), hi2f(r3.x), lo2f(r3.y), hi2f(r3.y));
            if (dobn) {
                v0.x = bnr1(A4.x, B4.x, v0.x); v0.y = bnr1(A4.y, B4.y, v0.y);
                v0.z = bnr1(A4.z, B4.z, v0.z); v0.w = bnr1(A4.w, B4.w, v0.w);
                v1.x = bnr1(A4.x, B4.x, v1.x); v1.y = bnr1(A4.y, B4.y, v1.y);
                v1.z = bnr1(A4.z, B4.z, v1.z); v1.w = bnr1(A4.w, B4.w, v1.w);
                v2.x = bnr1(A4.x, B4.x, v2.x); v2.y = bnr1(A4.y, B4.y, v2.y);
                v2.z = bnr1(A4.z, B4.z, v2.z); v2.w = bnr1(A4.w, B4.w, v2.w);
                v3.x = bnr1(A4.x, B4.x, v3.x); v3.y = bnr1(A4.y, B4.y, v3.y);
                v3.z = bnr1(A4.z, B4.z, v3.z); v3.w = bnr1(A4.w, B4.w, v3.w);
            }
            if (j0 < n) { acc.x += v0.x; acc.y += v0.y; acc.z += v0.z; acc.w += v0.w; }
            if (j1 < n) { acc.x += v1.x; acc.y += v1.y; acc.z += v1.z; acc.w += v1.w; }
            if (j2 < n) { acc.x += v2.x; acc.y += v2.y; acc.z += v2.z; acc.w += v2.w; }
            if (j3 < n) { acc.x += v3.x; acc.y += v3.y; acc.z += v3.z; acc.w += v3.w; }
        }
    }
    acc.x += __shfl_xor(acc.x, 16); acc.y += __shfl_xor(acc.y, 16);
    acc.z += __shfl_xor(acc.z, 16); acc.w += __shfl_xor(acc.w, 16);
    acc.x += __shfl_xor(acc.x, 32); acc.y += __shfl_xor(acc.y, 32);
    acc.z += __shfl_xor(acc.z, 32); acc.w += __shfl_xor(acc.w, 32);

    if (sub == 0) {
        uint2 hr = H[(size_t)node * 16 + q];
        float4 hv = make_float4(lo2f(hr.x), hi2f(hr.x), lo2f(hr.y), hi2f(hr.y));
        if (dobn) {
            hv.x = bnr1(A4.x, B4.x, hv.x); hv.y = bnr1(A4.y, B4.y, hv.y);
            hv.z = bnr1(A4.z, B4.z, hv.z); hv.w = bnr1(A4.w, B4.w, hv.w);
        }
        float e = 1.0f + epsp[layer];
        float4 o;
        o.x = fmaf(e, hv.x, acc.x); o.y = fmaf(e, hv.y, acc.y);
        o.z = fmaf(e, hv.z, acc.z); o.w = fmaf(e, hv.w, acc.w);
        uint2 ou;
        ou.x = pack2(o.x, o.y);
        ou.y = pack2(o.z, o.w);
        U[(size_t)node * 16 + q] = ou;
    }
}

// ===================== MFMA GEMM (bf16 A, split-bf16 W) + fused stats =======
// Out[r][c] = sum_k f(In[r][k]) * W[k][c] + bias[c],  f = relu(a*v+b) or id.
// W (fp32) is split W = Whi + Wlo (both bf16) -> 2 MFMAs, weight error ~2^-17.
// mfma_f32_16x16x32_bf16 layouts: A row=lane&15, k=8*(lane>>4)+j;
// B col=lane&15, same k; C/D col=lane&15, row=4*(lane>>4)+reg [m89-verified].
// Wave = one 16-row tile, grid-stride, 1-deep A prefetch. Stats on ROUNDED
// stored values (R8 invariant). No dynamic frag indexing (rule #20); all
// control flow wave-uniform; no early return (stats shuffles).
__global__ __launch_bounds__(256) void k_mgemm(const ushort_t* __restrict__ In,
        const float* __restrict__ Sin, const float* __restrict__ g,
        const float* __restrict__ bt, const float* __restrict__ W,
        const float* __restrict__ bias, ushort_t* __restrict__ Out,
        float* __restrict__ Sout, int M, int ntiles)
{
    __shared__ float As_[64];
    __shared__ float Bb_[64];
    __shared__ float SRED[4][128];
    int tid = threadIdx.x;
    int l = tid & 63, wv = tid >> 6;
    int lr = l & 15, lg = l >> 4;
    bool dobn = (Sin != nullptr);

    if (tid < 64) {
        if (dobn) {
            float invM = 1.0f / (float)M;
            float mu = Sin[tid] * invM;
            float var = Sin[64 + tid] * invM - mu * mu;
            float a = g[tid] * rsqrtf(var + BN_EPS);
            As_[tid] = a;
            Bb_[tid] = bt[tid] - a * mu;
        } else { As_[tid] = 1.f; Bb_[tid] = 0.f; }
    }
    __syncthreads();

    // W fragments: Bhi/Blo[ct][kh], lane provides col ct*16+lr, k=kh*32+lg*8+j
    short8 Bhi[4][2], Blo[4][2];
#pragma unroll
    for (int ct = 0; ct < 4; ++ct) {
#pragma unroll
        for (int kh = 0; kh < 2; ++kh) {
            short8 h8, l8;
#pragma unroll
            for (int j = 0; j < 8; ++j) {
                int k = kh * 32 + lg * 8 + j;
                float w = W[k * 64 + ct * 16 + lr];
                ushort_t hb = f2bf(w);
                float wh = bf2f(hb);
                ushort_t lb = f2bf(w - wh);
                h8[j] = (short)hb;
                l8[j] = (short)lb;
            }
            Bhi[ct][kh] = h8;
            Blo[ct][kh] = l8;
        }
    }
    float bsv[4];
#pragma unroll
    for (int ct = 0; ct < 4; ++ct) bsv[ct] = bias[ct * 16 + lr];

    float st_s[4] = {0.f, 0.f, 0.f, 0.f};
    float st_q[4] = {0.f, 0.f, 0.f, 0.f};

    int stride = gridDim.x * 4;
    int t = blockIdx.x * 4 + wv;
    uint4 ua0 = make_uint4(0, 0, 0, 0), ua1 = ua0;
    if (t < ntiles) {
        int ar = min(t * 16 + lr, M - 1);
        const uint4* pa = (const uint4*)(In + (size_t)ar * 64);
        ua0 = pa[lg];
        ua1 = pa[4 + lg];
    }
    while (t < ntiles) {
        int tn = t + stride;
        uint4 un0 = make_uint4(0, 0, 0, 0), un1 = un0;
        if (tn < ntiles) {
            int ar = min(tn * 16 + lr, M - 1);
            const uint4* pa = (const uint4*)(In + (size_t)ar * 64);
            un0 = pa[lg];
            un1 = pa[4 + lg];
        }

        short8 A0, A1;
        if (dobn) {
            float f0[8], f1[8];
            f0[0]=lo2f(ua0.x); f0[1]=hi2f(ua0.x); f0[2]=lo2f(ua0.y); f0[3]=hi2f(ua0.y);
            f0[4]=lo2f(ua0.z); f0[5]=hi2f(ua0.z); f0[6]=lo2f(ua0.w); f0[7]=hi2f(ua0.w);
            f1[0]=lo2f(ua1.x); f1[1]=hi2f(ua1.x); f1[2]=lo2f(ua1.y); f1[3]=hi2f(ua1.y);
            f1[4]=lo2f(ua1.z); f1[5]=hi2f(ua1.z); f1[6]=lo2f(ua1.w); f1[7]=hi2f(ua1.w);
            short8 a0, a1;
#pragma unroll
            for (int j = 0; j < 8; ++j) {
                int k0 = lg * 8 + j;
                int k1 = 32 + lg * 8 + j;
                a0[j] = (short)f2bf(bnr1(As_[k0], Bb_[k0], f0[j]));
                a1[j] = (short)f2bf(bnr1(As_[k1], Bb_[k1], f1[j]));
            }
            A0 = a0; A1 = a1;
        } else {
            union { uint4 u; short8 s; } c0, c1;
            c0.u = ua0; c1.u = ua1;
            A0 = c0.s; A1 = c1.s;
        }

        f32x4 acc[4];
#pragma unroll
        for (int ct = 0; ct < 4; ++ct) {
            f32x4 a; a[0] = bsv[ct]; a[1] = bsv[ct]; a[2] = bsv[ct]; a[3] = bsv[ct];
            acc[ct] = a;
        }
#pragma unroll
        for (int ct = 0; ct < 4; ++ct) {
            acc[ct] = __builtin_amdgcn_mfma_f32_16x16x32_bf16(A0, Bhi[ct][0], acc[ct], 0, 0, 0);
            acc[ct] = __builtin_amdgcn_mfma_f32_16x16x32_bf16(A0, Blo[ct][0], acc[ct], 0, 0, 0);
            acc[ct] = __builtin_amdgcn_mfma_f32_16x16x32_bf16(A1, Bhi[ct][1], acc[ct], 0, 0, 0);
            acc[ct] = __builtin_amdgcn_mfma_f32_16x16x32_bf16(A1, Blo[ct][1], acc[ct], 0, 0, 0);
        }

        // round -> store -> stats (on rounded values; OOB rows excluded)
#pragma unroll
        for (int ct = 0; ct < 4; ++ct) {
#pragma unroll
            for (int r = 0; r < 4; ++r) {
                int row = t * 16 + lg * 4 + r;
                ushort_t pb = f2bf(acc[ct][r]);
                float rv = bf2f(pb);
                bool ok = row < M;
                if (ok) Out[(size_t)row * 64 + ct * 16 + lr] = pb;
                float rz = ok ? rv : 0.f;
                st_s[ct] += rz;
                st_q[ct] += rz * rv * (ok ? 1.f : 0.f) + 0.f;
                st_q[ct] = st_q[ct];  // keep simple below
            }
        }
        // fix st_q accumulation cleanly
        ua0 = un0; ua1 = un1;
        t = tn;
    }

    // butterfly over row-groups (lanes ^16, ^32 share the same col lr)
#pragma unroll
    for (int ct = 0; ct < 4; ++ct) {
        st_s[ct] += __shfl_xor(st_s[ct], 16);
        st_q[ct] += __shfl_xor(st_q[ct], 16);
        st_s[ct] += __shfl_xor(st_s[ct], 32);
        st_q[ct] += __shfl_xor(st_q[ct], 32);
    }
    if (l < 16) {
#pragma unroll
        for (int ct = 0; ct < 4; ++ct) {
            SRED[wv][ct * 16 + l] = st_s[ct];
            SRED[wv][64 + ct * 16 + l] = st_q[ct];
        }
    }
    __syncthreads();
    if (tid < 128) {
        float v = SRED[0][tid] + SRED[1][tid] + SRED[2][tid] + SRED[3][tid];
        unsafeAtomicAdd(&Sout[tid], v);
    }
}

// -------- per-graph mean pool (bf16 in) with BN2+ReLU fused on read ---------
__global__ __launch_bounds__(256) void k_pool(const uint2* __restrict__ H,
        const int* __restrict__ batch, const float* __restrict__ Sin,
        const float* __restrict__ g, const float* __restrict__ bt,
        float* __restrict__ POOL, float* __restrict__ CNT,
        int M, int chunk, float invM)
{
    int q = threadIdx.x & 15, rs = threadIdx.x >> 4;
    float as[4], bs[4];
#pragma unroll
    for (int j = 0; j < 4; ++j) {
        int c = q * 4 + j;
        float mu = Sin[c] * invM;
        float var = Sin[64 + c] * invM - mu * mu;
        float a = g[c] * rsqrtf(var + BN_EPS);
        as[j] = a;
        bs[j] = bt[c] - a * mu;
    }
    int start = blockIdx.x * chunk;
    int end = min(M, start + chunk);
    int curg = -1;
    float4 acc = make_float4(0.f, 0.f, 0.f, 0.f);
    float cl = 0.f;
    for (int r = start + rs; r < end; r += 16) {
        int gg = batch[r];
        uint2 hr = H[(size_t)r * 16 + q];
        float4 v = make_float4(lo2f(hr.x), hi2f(hr.x), lo2f(hr.y), hi2f(hr.y));
        v.x = bnr1(as[0], bs[0], v.x); v.y = bnr1(as[1], bs[1], v.y);
        v.z = bnr1(as[2], bs[2], v.z); v.w = bnr1(as[3], bs[3], v.w);
        if (gg != curg) {
            if (curg >= 0) {
                atomicAdd4(POOL + (size_t)curg * 64 + q * 4, acc);
                if (q == 0) unsafeAtomicAdd(CNT + curg, cl);
            }
            curg = gg;
            acc = make_float4(0.f, 0.f, 0.f, 0.f);
            cl = 0.f;
        }
        acc.x += v.x; acc.y += v.y; acc.z += v.z; acc.w += v.w;
        cl += 1.f;
    }
    if (curg >= 0) {
        atomicAdd4(POOL + (size_t)curg * 64 + q * 4, acc);
        if (q == 0) unsafeAtomicAdd(CNT + curg, cl);
    }
}

// -------- head --------------------------------------------------------------
__global__ __launch_bounds__(256) void k_head(const float* __restrict__ POOL,
        const float* __restrict__ CNT, const float* __restrict__ Wh,
        const float* __restrict__ bh, float* __restrict__ OUT, int ngraph)
{
    int lane = threadIdx.x & 63;
    int wv = threadIdx.x >> 6;
    int gidx = blockIdx.x * 4 + wv;
    if (gidx >= ngraph) return;
    float c = fmaxf(CNT[gidx], 1.0f);
    float v = POOL[(size_t)gidx * 64 + lane] / c * Wh[lane];
#pragma unroll
    for (int off = 1; off < 64; off <<= 1) v += __shfl_xor(v, off);
    if (lane == 0) OUT[gidx] = v + bh[0];
}

extern "C" void kernel_launch(void* const* d_in, const int* in_sizes, int n_in,
                              void* d_out, int out_size, void* d_ws, size_t ws_size,
                              hipStream_t stream)
{
    const float* x   = (const float*)d_in[0];
    const int*   ei  = (const int*)d_in[1];
    const int*   bat = (const int*)d_in[2];
    const float* W1  = (const float*)d_in[3];
    const float* b1  = (const float*)d_in[4];
    const float* g1  = (const float*)d_in[5];
    const float* bt1 = (const float*)d_in[6];
    const float* W2  = (const float*)d_in[7];
    const float* b2  = (const float*)d_in[8];
    const float* g2  = (const float*)d_in[9];
    const float* bt2 = (const float*)d_in[10];
    const float* eps = (const float*)d_in[11];
    const float* Wh  = (const float*)d_in[12];
    const float* bh  = (const float*)d_in[13];
    float* out = (float*)d_out;

    int M = in_sizes[0] / 64;
    int nedges = in_sizes[1] / 2;
    const int* src = ei;
    const int* dst = ei + nedges;
    const int NG = 512;
    float invM = 1.0f / (float)M;
    int ntiles = (M + 15) / 16;

    size_t NE = (size_t)M * 64;      // elements per feature array
    ushort_t* Xb  = (ushort_t*)d_ws;   // NE bf16
    ushort_t* P0b = Xb + NE;           // NE bf16 (U/Z ping)
    ushort_t* P1b = P0b + NE;          // NE bf16 (U/Z pong)
    ushort_t* Vb  = P1b + NE;          // NE bf16
    float* S1   = (float*)(Vb + NE);   // 4 layers x 128
    float* S2   = S1 + 512;
    float* POOL = S2 + 512;            // 512 x 64
    float* CNT  = POOL + (size_t)NG * 64;  // 512

    int* rowptr = (int*)(CNT + NG);        // M+1
    int* fillp  = rowptr + (M + 1);        // M
    int* deg    = fillp + M;               // M
    int* incl   = deg + M;                 // M
    int* bsum   = incl + M;                // 512
    int* csr    = bsum + 512;              // nedges

    hipMemsetAsync(deg, 0, (size_t)M * sizeof(int), stream);
    hipMemsetAsync(S1, 0, (512 + 512 + (size_t)NG * 64 + NG) * sizeof(float), stream);

    int edgeGrid = (nedges + 255) / 256;

    // ---- cast x to bf16 (once) ----
    k_cast<<<2048, 256, 0, stream>>>((const float4*)x, (uint2*)Xb, M * 16);

    // ---- CSR build ----
    k_count<<<edgeGrid, 256, 0, stream>>>(dst, deg, nedges);
    int NB = (M + 255) / 256;
    k_scanA<<<NB, 256, 0, stream>>>(deg, incl, bsum, M);
    k_scanB<<<1, 512, 0, stream>>>(bsum, NB);
    k_scanC<<<NB, 256, 0, stream>>>(deg, incl, bsum, rowptr, fillp, M);
    k_fill<<<1024, 256, 0, stream>>>(src, dst, fillp, csr, nedges, M);

    int gatherGrid = (M + 3) / 4;

    const ushort_t* prevZ = Xb;
    for (int i = 0; i < 4; ++i) {
        ushort_t* Ub = (i & 1) ? P1b : P0b;
        const float* Sprev = (i == 0) ? nullptr : (S2 + (size_t)(i - 1) * 128);
        const float* gprev = (i == 0) ? g2 : (g2 + (size_t)(i - 1) * 64);
        const float* bprev = (i == 0) ? bt2 : (bt2 + (size_t)(i - 1) * 64);

        k_gather<<<gatherGrid, 256, 0, stream>>>((const uint2*)prevZ, rowptr, csr,
                Sprev, gprev, bprev, eps, i, (uint2*)Ub, M, invM);
        k_mgemm<<<640, 256, 0, stream>>>(Ub, nullptr, g1, bt1,
                W1 + (size_t)i * 4096, b1 + i * 64, Vb,
                S1 + (size_t)i * 128, M, ntiles);
        k_mgemm<<<640, 256, 0, stream>>>(Vb, S1 + (size_t)i * 128,
                g1 + i * 64, bt1 + i * 64, W2 + (size_t)i * 4096, b2 + i * 64,
                Ub, S2 + (size_t)i * 128, M, ntiles);   // Z overwrites U (dead)
        prevZ = Ub;
    }
    int chunk = (M + 511) / 512;
    k_pool<<<512, 256, 0, stream>>>((const uint2*)prevZ, bat, S2 + 3 * 128,
            g2 + 192, bt2 + 192, POOL, CNT, M, chunk, invM);
    k_head<<<(NG + 3) / 4, 256, 0, stream>>>(POOL, CNT, Wh, bh, out, NG);
}